// Round 8
// baseline (746.912 us; speedup 1.0000x reference)
//
#include <hip/hip_runtime.h>

// ConvRecLayer: dynamic conv (H=16, K=15, causal) + LayerNorm + FFN(relu) + residual
// T=1024 B=8 C=1024 F=4096. Inputs/outputs fp32 (per reference); internal compute bf16 MFMA.
//
// Round-8 notes:
//  - gemm_bt switched to m97-style SINGLE-buffered LDS (32 KiB) with 2 barriers
//    per K-step: barrier(DMA k done) -> ds_read frags -> barrier(reads done) ->
//    DMA k+1 into same buffer -> MFMA overlapping DMA. Occupancy 2 -> 4
//    blocks/CU (VGPR=88 caps at 4): doubles the drain-overlap partners.
//    Evidence: m97 single-buf ~3 blk/CU = 874-912 TF vs our dbuf 842; r0-r7
//    established the kernel is NOT fetch-bound (FETCH 82 vs 219 MB = same time).
//  - Everything else byte-identical to r7 (passed): prep weights-only,
//    gemm_a32 reg-staged wscore from fp32 x, conv_ln16s fp32-x staging.

#define T_DIM 1024
#define B_DIM 8
#define C_DIM 1024
#define F_DIM 4096
#define H_DIM 16
#define K_TAP 15
#define TB (T_DIM * B_DIM)   // 8192 rows

typedef __attribute__((ext_vector_type(8))) short short8;
typedef __attribute__((ext_vector_type(4))) float f32x4;

__device__ __forceinline__ float bf2f(unsigned short u) {
    union { unsigned int i; float f; } v; v.i = ((unsigned int)u) << 16; return v.f;
}
__device__ __forceinline__ unsigned short f2bf(float f) {
    union { float f; unsigned int i; } v; v.f = f;
    unsigned int r = v.i + 0x7fffu + ((v.i >> 16) & 1u);  // RNE
    return (unsigned short)(r >> 16);
}

// async global->LDS DMA, 16B per lane: lane i reads gptr(lane-dependent) and
// hardware stores to (wave-uniform lptr) + lane*16
__device__ __forceinline__ void async_copy16(const void* gptr, void* lptr) {
    __builtin_amdgcn_global_load_lds(
        (const __attribute__((address_space(1))) void*)gptr,
        (__attribute__((address_space(3))) void*)lptr, 16, 0, 0);
}

// ---------------------------------------------------------------------------
// prep: three fp32->bf16 transposes (weights only; x is consumed fp32 now).
// Grid (256 threads each, 2112 blocks):
//   [0, 1024)      fc1_w (C x F) -> fc1T (F x C), 64x64 tiles (64 ctiles, 16 rtiles)
//   [1024, 2048)   fc2_w (F x C) -> fc2T (C x F), 64x64 tiles (16, 64)
//   [2048, 2112)   w_lin (C x 240) -> wlinT (256 x C), rows 240..255 zero
// ---------------------------------------------------------------------------
__global__ __launch_bounds__(256)
void prep(const float* __restrict__ fc1_w, unsigned short* __restrict__ fc1T,
          const float* __restrict__ fc2_w, unsigned short* __restrict__ fc2T,
          const float* __restrict__ w_lin, unsigned short* __restrict__ wlinT) {
    const int bid = blockIdx.x;
    const int tid = threadIdx.x;
    const float* in; unsigned short* out; int R, Cin, c0, r0;
    if (bid < 1024) {
        int idx = bid;                        // grid (64 ctiles, 16 rtiles)
        in = fc1_w; out = fc1T; R = C_DIM; Cin = F_DIM;
        c0 = (idx & 63) * 64; r0 = (idx >> 6) * 64;
    } else if (bid < 2048) {
        int idx = bid - 1024;                 // grid (16, 64)
        in = fc2_w; out = fc2T; R = F_DIM; Cin = C_DIM;
        c0 = (idx & 15) * 64; r0 = (idx >> 4) * 64;
    } else {
        int idx = bid - 2048;                 // grid (4, 16)
        in = w_lin; out = wlinT; R = C_DIM; Cin = 240;
        c0 = (idx & 3) * 64; r0 = (idx >> 2) * 64;
    }
    __shared__ unsigned short tile[64][65];
    const int xx = tid & 63, yy = tid >> 6;   // 64 x 4
#pragma unroll
    for (int j = 0; j < 16; j++) {
        int r = r0 + yy + j * 4, c = c0 + xx;
        unsigned short v = 0;
        if (c < Cin) v = f2bf(in[(size_t)r * Cin + c]);
        tile[yy + j * 4][xx] = v;
    }
    __syncthreads();
#pragma unroll
    for (int j = 0; j < 16; j++) {
        out[(size_t)(c0 + yy + j * 4) * R + (r0 + xx)] = tile[xx][yy + j * 4];
    }
}

// ---------------------------------------------------------------------------
// gemm_bt: C[M x N] = A[M x K] @ Bt[N x K]^T  (bf16 in, fp32 acc)
// 128x128 block tile, 4 waves each computing 64x64 via 4x4 MFMA 16x16x32 tiles.
// m97-style SINGLE-buffered LDS (32 KiB -> 4 blocks/CU), 2 barriers/K-step:
//   barrier1: DMA of tile k landed (syncthreads drains vmcnt)
//   ds_read all fragments to regs
//   barrier2: every wave's reads complete -> LDS safe to overwrite
//   issue DMA tile k+1 (overlaps the MFMA below)
//   32 MFMA from registers
// LDS tile [128 r][64 k]: chunk c of row r stored at slot c ^ (r&7)
// (swizzle on the GLOBAL address side; DMA LDS dest is lane-contiguous).
// SWAP=0: (x=n, y=m)   SWAP=1: (x=m, y=n)
// MODE 1: bf16 out = relu(acc + bias[n])
// MODE 2: fp32 out = acc + bias[n] + resid[m][n]   (resid bf16)
// ---------------------------------------------------------------------------
template <int MODE, int SWAP>
__global__ __launch_bounds__(256, 4)
void gemm_bt(const unsigned short* __restrict__ A,
             const unsigned short* __restrict__ Bt,
             void* __restrict__ Cout_v,
             int M, int N, int K, int kz,
             const float* __restrict__ bias,
             const unsigned short* __restrict__ resid) {
    __shared__ __align__(16) unsigned short As[128 * 64];
    __shared__ __align__(16) unsigned short Bs[128 * 64];

    const int tid = threadIdx.x;
    const int m0 = (SWAP ? blockIdx.x : blockIdx.y) * 128;
    const int n0 = (SWAP ? blockIdx.y : blockIdx.x) * 128;
    const int kbase = blockIdx.z * kz;
    const int wave = tid >> 6, lane = tid & 63;
    const int quad = lane >> 4, l16 = lane & 15;
    const int wm = (wave >> 1) * 64;  // wave row offset in tile
    const int wn = (wave & 1) * 64;   // wave col offset in tile

    f32x4 acc[4][4];
#pragma unroll
    for (int i = 0; i < 4; i++)
#pragma unroll
        for (int j = 0; j < 4; j++) acc[i][j] = (f32x4){0.f, 0.f, 0.f, 0.f};

    const int rsub = lane >> 3;                   // 0..7
    const int gch = (lane & 7) ^ rsub;            // swizzled global chunk
    const unsigned short* gA = A + (size_t)(m0 + wave * 32 + rsub) * K + kbase + gch * 8;
    const unsigned short* gB = Bt + (size_t)(n0 + wave * 32 + rsub) * K + kbase + gch * 8;
    unsigned short* lA = &As[wave * 32 * 64];
    unsigned short* lB = &Bs[wave * 32 * 64];

    // prologue: stage tile 0
#pragma unroll
    for (int j = 0; j < 4; j++) {
        async_copy16(gA + (size_t)j * 8 * K, lA + j * 8 * 64);
        async_copy16(gB + (size_t)j * 8 * K, lB + j * 8 * 64);
    }

    const int swz = l16 & 7;                      // fragment-read swizzle
    for (int k0 = 0; k0 < kz; k0 += 64) {
        __syncthreads();   // barrier1: DMA of tile k0 landed (vmcnt drained)

        short8 af[2][4], bfr[2][4];
#pragma unroll
        for (int kk = 0; kk < 2; kk++) {
            const int c = kk * 4 + quad;          // global chunk for this kk
#pragma unroll
            for (int i = 0; i < 4; i++) {
                af[kk][i]  = *(const short8*)(&As[(wm + i * 16 + l16) * 64 + (c ^ swz) * 8]);
                bfr[kk][i] = *(const short8*)(&Bs[(wn + i * 16 + l16) * 64 + (c ^ swz) * 8]);
            }
        }
        __syncthreads();   // barrier2: all waves' frag reads done -> LDS reusable

        const int nk = k0 + 64;
        if (nk < kz) {     // DMA tile k+1 into the (single) buffer; overlaps MFMA
#pragma unroll
            for (int j = 0; j < 4; j++) {
                async_copy16(gA + nk + (size_t)j * 8 * K, lA + j * 8 * 64);
                async_copy16(gB + nk + (size_t)j * 8 * K, lB + j * 8 * 64);
            }
        }

#pragma unroll
        for (int kk = 0; kk < 2; kk++)
#pragma unroll
            for (int mi = 0; mi < 4; mi++)
#pragma unroll
                for (int nj = 0; nj < 4; nj++)
                    acc[mi][nj] = __builtin_amdgcn_mfma_f32_16x16x32_bf16(
                        af[kk][mi], bfr[kk][nj], acc[mi][nj], 0, 0, 0);
    }

    // epilogue: lane holds D[row=quad*4+i][col=l16] per 16x16 tile
    const int crow0 = m0 + wm + quad * 4;
    const int ccol0 = n0 + wn + l16;
    if (MODE == 1) {
        unsigned short* Cb = (unsigned short*)Cout_v;
        float bv[4];
#pragma unroll
        for (int nj = 0; nj < 4; nj++) bv[nj] = bias[ccol0 + nj * 16];
#pragma unroll
        for (int mi = 0; mi < 4; mi++)
#pragma unroll
            for (int i = 0; i < 4; i++) {
                int rr = crow0 + mi * 16 + i;
#pragma unroll
                for (int nj = 0; nj < 4; nj++) {
                    float v = fmaxf(acc[mi][nj][i] + bv[nj], 0.f);
                    Cb[(size_t)rr * N + ccol0 + nj * 16] = f2bf(v);
                }
            }
    } else {  // MODE 2
        float* Cf = (float*)Cout_v;
        float bv[4];
#pragma unroll
        for (int nj = 0; nj < 4; nj++) bv[nj] = bias[ccol0 + nj * 16];
#pragma unroll
        for (int mi = 0; mi < 4; mi++)
#pragma unroll
            for (int i = 0; i < 4; i++) {
                int rr = crow0 + mi * 16 + i;
#pragma unroll
                for (int nj = 0; nj < 4; nj++) {
                    float v = acc[mi][nj][i] + bv[nj]
                            + bf2f(resid[(size_t)rr * N + ccol0 + nj * 16]);
                    Cf[(size_t)rr * N + ccol0 + nj * 16] = v;
                }
            }
    }
}

// ---------------------------------------------------------------------------
// gemm_a32: wscore GEMM reading fp32 A directly (unchanged from r7, verified).
// C[M x N] = A32[M x K] @ Bt[N x K]^T, fp32 partial out per blockIdx.z.
// 128^2 / BK=64 / 4-wave skeleton; B via DMA; A reg-staged (fp32 load ->
// bf16 convert -> swizzled ds_write), double-buffered, 1 barrier/iter.
// ---------------------------------------------------------------------------
__global__ __launch_bounds__(256)
void gemm_a32(const float* __restrict__ A32,
              const unsigned short* __restrict__ Bt,
              float* __restrict__ Cout,
              int M, int N, int K, int kz) {
    __shared__ __align__(16) unsigned short As[2][128 * 64];
    __shared__ __align__(16) unsigned short Bs[2][128 * 64];

    const int tid = threadIdx.x;
    const int m0 = blockIdx.y * 128;
    const int n0 = blockIdx.x * 128;
    const int kbase = blockIdx.z * kz;
    const int wave = tid >> 6, lane = tid & 63;
    const int quad = lane >> 4, l16 = lane & 15;
    const int wm = (wave >> 1) * 64;
    const int wn = (wave & 1) * 64;

    f32x4 acc[4][4];
#pragma unroll
    for (int i = 0; i < 4; i++)
#pragma unroll
        for (int j = 0; j < 4; j++) acc[i][j] = (f32x4){0.f, 0.f, 0.f, 0.f};

    // A reg-staging geometry: thread t -> row ar = t>>1 (0..127), half ah = t&1
    const int ar = tid >> 1, ah = tid & 1;
    const float* gAf = A32 + (size_t)(m0 + ar) * K + kbase + ah * 32;

    // B DMA geometry (identical to gemm_bt)
    const int rsub = lane >> 3;
    const int gch = (lane & 7) ^ rsub;
    const unsigned short* gB = Bt + (size_t)(n0 + wave * 32 + rsub) * K + kbase + gch * 8;
    unsigned short* lB[2] = {&Bs[0][wave * 32 * 64], &Bs[1][wave * 32 * 64]};

    // stage A k-chunk [k0, k0+64) of this thread's row into buffer bb
    auto stageA = [&](int k0, int bb) {
#pragma unroll
        for (int c = 0; c < 4; c++) {
            float4 a = *(const float4*)(gAf + k0 + c * 8);
            float4 b = *(const float4*)(gAf + k0 + c * 8 + 4);
            uint4 o;
            o.x = (unsigned int)f2bf(a.x) | ((unsigned int)f2bf(a.y) << 16);
            o.y = (unsigned int)f2bf(a.z) | ((unsigned int)f2bf(a.w) << 16);
            o.z = (unsigned int)f2bf(b.x) | ((unsigned int)f2bf(b.y) << 16);
            o.w = (unsigned int)f2bf(b.z) | ((unsigned int)f2bf(b.w) << 16);
            const int gc = ah * 4 + c;            // global chunk 0..7
            *(uint4*)(&As[bb][ar * 64 + ((gc ^ (ar & 7)) * 8)]) = o;
        }
    };

    // prologue: stage tile 0 into buffer 0
    stageA(0, 0);
#pragma unroll
    for (int j = 0; j < 4; j++)
        async_copy16(gB + (size_t)j * 8 * K, lB[0] + j * 8 * 64);

    const int swz = l16 & 7;
    int buf = 0;
    for (int k0 = 0; k0 < kz; k0 += 64) {
        __syncthreads();   // drains A ds_writes + B DMA (tile k) + reads of buf^1

        const int nk = k0 + 64;
        if (nk < kz) {
            const int nb = buf ^ 1;
            stageA(nk, nb);
#pragma unroll
            for (int j = 0; j < 4; j++)
                async_copy16(gB + nk + (size_t)j * 8 * K, lB[nb] + j * 8 * 64);
        }

        short8 af[2][4], bfr[2][4];
#pragma unroll
        for (int kk = 0; kk < 2; kk++) {
            const int c = kk * 4 + quad;
#pragma unroll
            for (int i = 0; i < 4; i++) {
                af[kk][i]  = *(const short8*)(&As[buf][(wm + i * 16 + l16) * 64 + (c ^ swz) * 8]);
                bfr[kk][i] = *(const short8*)(&Bs[buf][(wn + i * 16 + l16) * 64 + (c ^ swz) * 8]);
            }
        }
#pragma unroll
        for (int kk = 0; kk < 2; kk++)
#pragma unroll
            for (int mi = 0; mi < 4; mi++)
#pragma unroll
                for (int nj = 0; nj < 4; nj++)
                    acc[mi][nj] = __builtin_amdgcn_mfma_f32_16x16x32_bf16(
                        af[kk][mi], bfr[kk][nj], acc[mi][nj], 0, 0, 0);
        buf ^= 1;
    }

    // epilogue: fp32 partial out at z-offset
    float* Cf = Cout + (size_t)blockIdx.z * M * N;
    const int crow0 = m0 + wm + quad * 4;
    const int ccol0 = n0 + wn + l16;
#pragma unroll
    for (int mi = 0; mi < 4; mi++)
#pragma unroll
        for (int i = 0; i < 4; i++) {
            int rr = crow0 + mi * 16 + i;
#pragma unroll
            for (int nj = 0; nj < 4; nj++)
                Cf[(size_t)rr * N + ccol0 + nj * 16] = acc[mi][nj][i];
        }
}

// ---------------------------------------------------------------------------
// conv_ln16s: tap-softmax (2 split-K wscore partials) + causal dynamic conv
// + LayerNorm, 16 t-rows per block (512 blocks). Unchanged from r7 (verified).
// ---------------------------------------------------------------------------
#define XSP 1032   // padded LDS row stride (bf16 elems); 2064B, 16B-aligned
#define WS_STRIDE ((size_t)TB * 256)
__global__ __launch_bounds__(256)
void conv_ln16s(const float* __restrict__ x,
                const float* __restrict__ wscore,
                const float* __restrict__ b_lin,
                const float* __restrict__ ln_g,
                const float* __restrict__ ln_b,
                unsigned short* __restrict__ y) {
    __shared__ __align__(16) unsigned short xs[30 * XSP];   // 60.5 KiB
    __shared__ float wls[16 * 240];                         // 15 KiB
    const int blk = blockIdx.x;          // 0..511
    const int b = blk & 7;
    const int t0 = (blk >> 3) * 16;
    const int tid = threadIdx.x;
    const int wave = tid >> 6, lane = tid & 63;

    // phase 0: stage 30 x-rows, fp32 load + convert, 16B fp32 per thread per row
#pragma unroll
    for (int j = 0; j < 30; j++) {
        const int t = t0 + j - 14;
        uint2 o = make_uint2(0u, 0u);
        if (t >= 0) {
            float4 v = *(const float4*)(x + ((size_t)t * B_DIM + b) * C_DIM + tid * 4);
            o.x = (unsigned int)f2bf(v.x) | ((unsigned int)f2bf(v.y) << 16);
            o.y = (unsigned int)f2bf(v.z) | ((unsigned int)f2bf(v.w) << 16);
        }
        *(uint2*)(&xs[j * XSP + tid * 4]) = o;
    }

    // phase 1: per-(row, head) softmax from 2 split-K partials
    {
        const int row = tid >> 4, hh = tid & 15;
        const size_t grow = (size_t)(t0 + row) * B_DIM + b;
        const float* p = wscore + grow * 256 + hh * K_TAP;
        float v[K_TAP], mx = -1e30f;
#pragma unroll
        for (int k = 0; k < K_TAP; k++) {
            v[k] = p[k] + p[k + WS_STRIDE] + b_lin[hh * K_TAP + k];
            mx = fmaxf(mx, v[k]);
        }
        float s = 0.f;
#pragma unroll
        for (int k = 0; k < K_TAP; k++) { v[k] = __expf(v[k] - mx); s += v[k]; }
        float inv = 1.0f / s;
#pragma unroll
        for (int k = 0; k < K_TAP; k++) wls[row * 240 + hh * K_TAP + k] = v[k] * inv;
    }
    __syncthreads();

    // phase 2: conv + LN. wave handles rows wave, wave+4, wave+8, wave+12.
    const int chA = lane * 8;            // channels [chA, chA+8)
    const int chB = 512 + lane * 8;      // channels [chB, chB+8)
    const int hA = lane >> 3;            // head of chA block
    const int hB = 8 + (lane >> 3);      // head of chB block
    for (int rj = wave; rj < 16; rj += 4) {
        float o[16];
#pragma unroll
        for (int i = 0; i < 16; i++) o[i] = 0.f;
#pragma unroll
        for (int k = 0; k < K_TAP; k++) {
            float wA = wls[rj * 240 + hA * K_TAP + k];
            float wB = wls[rj * 240 + hB * K_TAP + k];
            const unsigned short* xr = &xs[(rj + k) * XSP];
            uint4 pA = *(const uint4*)(xr + chA);
            uint4 pB = *(const uint4*)(xr + chB);
            unsigned int ua[4] = {pA.x, pA.y, pA.z, pA.w};
            unsigned int ub[4] = {pB.x, pB.y, pB.z, pB.w};
#pragma unroll
            for (int q = 0; q < 4; q++) {
                o[2 * q]     += wA * bf2f((unsigned short)(ua[q] & 0xffff));
                o[2 * q + 1] += wA * bf2f((unsigned short)(ua[q] >> 16));
                o[8 + 2 * q]     += wB * bf2f((unsigned short)(ub[q] & 0xffff));
                o[8 + 2 * q + 1] += wB * bf2f((unsigned short)(ub[q] >> 16));
            }
        }
        float s = 0.f, s2 = 0.f;
#pragma unroll
        for (int i = 0; i < 16; i++) { s += o[i]; s2 += o[i] * o[i]; }
#pragma unroll
        for (int off = 32; off > 0; off >>= 1) {
            s  += __shfl_xor(s, off, 64);
            s2 += __shfl_xor(s2, off, 64);
        }
        float mu = s * (1.0f / C_DIM);
        float var = s2 * (1.0f / C_DIM) - mu * mu;
        float rs = rsqrtf(var + 1e-5f);

        unsigned short o16[16];
#pragma unroll
        for (int i = 0; i < 8; i++)
            o16[i] = f2bf((o[i] - mu) * rs * ln_g[chA + i] + ln_b[chA + i]);
#pragma unroll
        for (int i = 0; i < 8; i++)
            o16[8 + i] = f2bf((o[8 + i] - mu) * rs * ln_g[chB + i] + ln_b[chB + i]);
        uint4 w0, w1;
        w0.x = (unsigned int)o16[0]  | ((unsigned int)o16[1]  << 16);
        w0.y = (unsigned int)o16[2]  | ((unsigned int)o16[3]  << 16);
        w0.z = (unsigned int)o16[4]  | ((unsigned int)o16[5]  << 16);
        w0.w = (unsigned int)o16[6]  | ((unsigned int)o16[7]  << 16);
        w1.x = (unsigned int)o16[8]  | ((unsigned int)o16[9]  << 16);
        w1.y = (unsigned int)o16[10] | ((unsigned int)o16[11] << 16);
        w1.z = (unsigned int)o16[12] | ((unsigned int)o16[13] << 16);
        w1.w = (unsigned int)o16[14] | ((unsigned int)o16[15] << 16);
        unsigned short* yr = y + ((size_t)(t0 + rj) * B_DIM + b) * C_DIM;
        *(uint4*)(yr + chA) = w0;
        *(uint4*)(yr + chB) = w1;
    }
}

// ---------------------------------------------------------------------------
extern "C" void kernel_launch(void* const* d_in, const int* in_sizes, int n_in,
                              void* d_out, int out_size, void* d_ws, size_t ws_size,
                              hipStream_t stream) {
    const float* x     = (const float*)d_in[0];
    const float* w_lin = (const float*)d_in[1];
    const float* b_lin = (const float*)d_in[2];
    const float* ln_g  = (const float*)d_in[3];
    const float* ln_b  = (const float*)d_in[4];
    const float* fc1_w = (const float*)d_in[5];
    const float* fc1_b = (const float*)d_in[6];
    const float* fc2_w = (const float*)d_in[7];
    const float* fc2_b = (const float*)d_in[8];
    float* out = (float*)d_out;

    // workspace layout (bytes); ~98 MiB total
    char* ws = (char*)d_ws;
    unsigned short* fc1T  = (unsigned short*)(ws);                      // F x C     8 MiB
    unsigned short* fc2T  = (unsigned short*)(ws + 8388608);            // C x F     8 MiB
    unsigned short* wlinT = (unsigned short*)(ws + 16777216);           // 256 x C   0.5 MiB
    unsigned short* y     = (unsigned short*)(ws + 17301504);           // TB x C   16 MiB
    unsigned short* h     = (unsigned short*)(ws + 34078720);           // TB x F   64 MiB
    // wscore (2 split-K partials) overlaps h's region (dead before fc1)
    float* wscore = (float*)(ws + 34078720);                            // 2 x TB x 256 fp32 (16 MiB)

    // weight transposes (1 launch)
    prep<<<2112, 256, 0, stream>>>(fc1_w, fc1T, fc2_w, fc2T, w_lin, wlinT);

    // conv-weight logits from fp32 x: wscore[z] = x @ wlinT K-slice (z=2, 256 blocks)
    gemm_a32<<<dim3(256 / 128, TB / 128, 2), 256, 0, stream>>>(
        x, wlinT, wscore, TB, 256, C_DIM, C_DIM / 2);

    // fused softmax + dynamic conv + LayerNorm -> y (bf16), 16 rows per block
    conv_ln16s<<<TB / 16, 256, 0, stream>>>(x, wscore, b_lin, ln_g, ln_b, y);

    // h = relu(y @ fc1_w + fc1_b)  (bf16)
    gemm_bt<1, 0><<<dim3(F_DIM / 128, TB / 128, 1), 256, 0, stream>>>(
        y, fc1T, (void*)h, TB, F_DIM, C_DIM, C_DIM, fc1_b, nullptr);

    // out = h @ fc2_w + fc2_b + y  (fp32); m-tile on x for same-XCD h reuse
    gemm_bt<2, 1><<<dim3(TB / 128, C_DIM / 128, 1), 256, 0, stream>>>(
        h, fc2T, (void*)out, TB, C_DIM, F_DIM, F_DIM, fc2_b, y);
}

// Round 9
// 290.007 us; speedup vs baseline: 2.5755x; 2.5755x over previous
//
#include <hip/hip_runtime.h>

// ConvRecLayer: dynamic conv (H=16, K=15, causal) + LayerNorm + FFN(relu) + residual
// T=1024 B=8 C=1024 F=4096. Inputs/outputs fp32 (per reference); internal compute bf16 MFMA.
//
// Round-9 notes:
//  - r8 failure root-caused: __launch_bounds__(256,4) capped regs at ~128 total;
//    64-AGPR acc left ~64 arch VGPRs -> 16 live fragments spilled (WRITE_SIZE
//    65->750 MB, VGPR 88->64, 317 us). The occupancy idea was never tested.
//  - This round: SAME single-buffered 2-barrier gemm_bt but plain
//    __launch_bounds__(256) — natural regalloc (~150-175 total incl. AGPR) ->
//    ~3 blocks/CU (vs dbuf's LDS-limited 2), no spill. m97 operating point.
//  - Everything else byte-identical to r7 (passed): prep weights-only,
//    gemm_a32 reg-staged wscore from fp32 x, conv_ln16s fp32-x staging.

#define T_DIM 1024
#define B_DIM 8
#define C_DIM 1024
#define F_DIM 4096
#define H_DIM 16
#define K_TAP 15
#define TB (T_DIM * B_DIM)   // 8192 rows

typedef __attribute__((ext_vector_type(8))) short short8;
typedef __attribute__((ext_vector_type(4))) float f32x4;

__device__ __forceinline__ float bf2f(unsigned short u) {
    union { unsigned int i; float f; } v; v.i = ((unsigned int)u) << 16; return v.f;
}
__device__ __forceinline__ unsigned short f2bf(float f) {
    union { float f; unsigned int i; } v; v.f = f;
    unsigned int r = v.i + 0x7fffu + ((v.i >> 16) & 1u);  // RNE
    return (unsigned short)(r >> 16);
}

// async global->LDS DMA, 16B per lane: lane i reads gptr(lane-dependent) and
// hardware stores to (wave-uniform lptr) + lane*16
__device__ __forceinline__ void async_copy16(const void* gptr, void* lptr) {
    __builtin_amdgcn_global_load_lds(
        (const __attribute__((address_space(1))) void*)gptr,
        (__attribute__((address_space(3))) void*)lptr, 16, 0, 0);
}

// ---------------------------------------------------------------------------
// prep: three fp32->bf16 transposes (weights only; x is consumed fp32 now).
// Grid (256 threads each, 2112 blocks):
//   [0, 1024)      fc1_w (C x F) -> fc1T (F x C), 64x64 tiles (64 ctiles, 16 rtiles)
//   [1024, 2048)   fc2_w (F x C) -> fc2T (C x F), 64x64 tiles (16, 64)
//   [2048, 2112)   w_lin (C x 240) -> wlinT (256 x C), rows 240..255 zero
// ---------------------------------------------------------------------------
__global__ __launch_bounds__(256)
void prep(const float* __restrict__ fc1_w, unsigned short* __restrict__ fc1T,
          const float* __restrict__ fc2_w, unsigned short* __restrict__ fc2T,
          const float* __restrict__ w_lin, unsigned short* __restrict__ wlinT) {
    const int bid = blockIdx.x;
    const int tid = threadIdx.x;
    const float* in; unsigned short* out; int R, Cin, c0, r0;
    if (bid < 1024) {
        int idx = bid;                        // grid (64 ctiles, 16 rtiles)
        in = fc1_w; out = fc1T; R = C_DIM; Cin = F_DIM;
        c0 = (idx & 63) * 64; r0 = (idx >> 6) * 64;
    } else if (bid < 2048) {
        int idx = bid - 1024;                 // grid (16, 64)
        in = fc2_w; out = fc2T; R = F_DIM; Cin = C_DIM;
        c0 = (idx & 15) * 64; r0 = (idx >> 4) * 64;
    } else {
        int idx = bid - 2048;                 // grid (4, 16)
        in = w_lin; out = wlinT; R = C_DIM; Cin = 240;
        c0 = (idx & 3) * 64; r0 = (idx >> 2) * 64;
    }
    __shared__ unsigned short tile[64][65];
    const int xx = tid & 63, yy = tid >> 6;   // 64 x 4
#pragma unroll
    for (int j = 0; j < 16; j++) {
        int r = r0 + yy + j * 4, c = c0 + xx;
        unsigned short v = 0;
        if (c < Cin) v = f2bf(in[(size_t)r * Cin + c]);
        tile[yy + j * 4][xx] = v;
    }
    __syncthreads();
#pragma unroll
    for (int j = 0; j < 16; j++) {
        out[(size_t)(c0 + yy + j * 4) * R + (r0 + xx)] = tile[xx][yy + j * 4];
    }
}

// ---------------------------------------------------------------------------
// gemm_bt: C[M x N] = A[M x K] @ Bt[N x K]^T  (bf16 in, fp32 acc)
// 128x128 block tile, 4 waves each computing 64x64 via 4x4 MFMA 16x16x32 tiles.
// m97-style SINGLE-buffered LDS (32 KiB), 2 barriers/K-step:
//   barrier1: DMA of tile k landed (syncthreads drains vmcnt)
//   ds_read all fragments to regs
//   barrier2: every wave's reads complete -> LDS safe to overwrite
//   issue DMA tile k+1 (overlaps the MFMA below)
//   32 MFMA from registers
// NO min-wave launch-bounds clause: r8's (256,4) capped regs and spilled the
// 16 live fragments (WRITE_SIZE 750 MB). Natural alloc -> ~3 blocks/CU.
// LDS tile [128 r][64 k]: chunk c of row r stored at slot c ^ (r&7)
// (swizzle on the GLOBAL address side; DMA LDS dest is lane-contiguous).
// SWAP=0: (x=n, y=m)   SWAP=1: (x=m, y=n)
// MODE 1: bf16 out = relu(acc + bias[n])
// MODE 2: fp32 out = acc + bias[n] + resid[m][n]   (resid bf16)
// ---------------------------------------------------------------------------
template <int MODE, int SWAP>
__global__ __launch_bounds__(256)
void gemm_bt(const unsigned short* __restrict__ A,
             const unsigned short* __restrict__ Bt,
             void* __restrict__ Cout_v,
             int M, int N, int K, int kz,
             const float* __restrict__ bias,
             const unsigned short* __restrict__ resid) {
    __shared__ __align__(16) unsigned short As[128 * 64];
    __shared__ __align__(16) unsigned short Bs[128 * 64];

    const int tid = threadIdx.x;
    const int m0 = (SWAP ? blockIdx.x : blockIdx.y) * 128;
    const int n0 = (SWAP ? blockIdx.y : blockIdx.x) * 128;
    const int kbase = blockIdx.z * kz;
    const int wave = tid >> 6, lane = tid & 63;
    const int quad = lane >> 4, l16 = lane & 15;
    const int wm = (wave >> 1) * 64;  // wave row offset in tile
    const int wn = (wave & 1) * 64;   // wave col offset in tile

    f32x4 acc[4][4];
#pragma unroll
    for (int i = 0; i < 4; i++)
#pragma unroll
        for (int j = 0; j < 4; j++) acc[i][j] = (f32x4){0.f, 0.f, 0.f, 0.f};

    const int rsub = lane >> 3;                   // 0..7
    const int gch = (lane & 7) ^ rsub;            // swizzled global chunk
    const unsigned short* gA = A + (size_t)(m0 + wave * 32 + rsub) * K + kbase + gch * 8;
    const unsigned short* gB = Bt + (size_t)(n0 + wave * 32 + rsub) * K + kbase + gch * 8;
    unsigned short* lA = &As[wave * 32 * 64];
    unsigned short* lB = &Bs[wave * 32 * 64];

    // prologue: stage tile 0
#pragma unroll
    for (int j = 0; j < 4; j++) {
        async_copy16(gA + (size_t)j * 8 * K, lA + j * 8 * 64);
        async_copy16(gB + (size_t)j * 8 * K, lB + j * 8 * 64);
    }

    const int swz = l16 & 7;                      // fragment-read swizzle
    for (int k0 = 0; k0 < kz; k0 += 64) {
        __syncthreads();   // barrier1: DMA of tile k0 landed (vmcnt drained)

        short8 af[2][4], bfr[2][4];
#pragma unroll
        for (int kk = 0; kk < 2; kk++) {
            const int c = kk * 4 + quad;          // global chunk for this kk
#pragma unroll
            for (int i = 0; i < 4; i++) {
                af[kk][i]  = *(const short8*)(&As[(wm + i * 16 + l16) * 64 + (c ^ swz) * 8]);
                bfr[kk][i] = *(const short8*)(&Bs[(wn + i * 16 + l16) * 64 + (c ^ swz) * 8]);
            }
        }
        __syncthreads();   // barrier2: all waves' frag reads done -> LDS reusable

        const int nk = k0 + 64;
        if (nk < kz) {     // DMA tile k+1 into the (single) buffer; overlaps MFMA
#pragma unroll
            for (int j = 0; j < 4; j++) {
                async_copy16(gA + nk + (size_t)j * 8 * K, lA + j * 8 * 64);
                async_copy16(gB + nk + (size_t)j * 8 * K, lB + j * 8 * 64);
            }
        }

#pragma unroll
        for (int kk = 0; kk < 2; kk++)
#pragma unroll
            for (int mi = 0; mi < 4; mi++)
#pragma unroll
                for (int nj = 0; nj < 4; nj++)
                    acc[mi][nj] = __builtin_amdgcn_mfma_f32_16x16x32_bf16(
                        af[kk][mi], bfr[kk][nj], acc[mi][nj], 0, 0, 0);
    }

    // epilogue: lane holds D[row=quad*4+i][col=l16] per 16x16 tile
    const int crow0 = m0 + wm + quad * 4;
    const int ccol0 = n0 + wn + l16;
    if (MODE == 1) {
        unsigned short* Cb = (unsigned short*)Cout_v;
        float bv[4];
#pragma unroll
        for (int nj = 0; nj < 4; nj++) bv[nj] = bias[ccol0 + nj * 16];
#pragma unroll
        for (int mi = 0; mi < 4; mi++)
#pragma unroll
            for (int i = 0; i < 4; i++) {
                int rr = crow0 + mi * 16 + i;
#pragma unroll
                for (int nj = 0; nj < 4; nj++) {
                    float v = fmaxf(acc[mi][nj][i] + bv[nj], 0.f);
                    Cb[(size_t)rr * N + ccol0 + nj * 16] = f2bf(v);
                }
            }
    } else {  // MODE 2
        float* Cf = (float*)Cout_v;
        float bv[4];
#pragma unroll
        for (int nj = 0; nj < 4; nj++) bv[nj] = bias[ccol0 + nj * 16];
#pragma unroll
        for (int mi = 0; mi < 4; mi++)
#pragma unroll
            for (int i = 0; i < 4; i++) {
                int rr = crow0 + mi * 16 + i;
#pragma unroll
                for (int nj = 0; nj < 4; nj++) {
                    float v = acc[mi][nj][i] + bv[nj]
                            + bf2f(resid[(size_t)rr * N + ccol0 + nj * 16]);
                    Cf[(size_t)rr * N + ccol0 + nj * 16] = v;
                }
            }
    }
}

// ---------------------------------------------------------------------------
// gemm_a32: wscore GEMM reading fp32 A directly (unchanged from r7, verified).
// C[M x N] = A32[M x K] @ Bt[N x K]^T, fp32 partial out per blockIdx.z.
// 128^2 / BK=64 / 4-wave skeleton; B via DMA; A reg-staged (fp32 load ->
// bf16 convert -> swizzled ds_write), double-buffered, 1 barrier/iter.
// ---------------------------------------------------------------------------
__global__ __launch_bounds__(256)
void gemm_a32(const float* __restrict__ A32,
              const unsigned short* __restrict__ Bt,
              float* __restrict__ Cout,
              int M, int N, int K, int kz) {
    __shared__ __align__(16) unsigned short As[2][128 * 64];
    __shared__ __align__(16) unsigned short Bs[2][128 * 64];

    const int tid = threadIdx.x;
    const int m0 = blockIdx.y * 128;
    const int n0 = blockIdx.x * 128;
    const int kbase = blockIdx.z * kz;
    const int wave = tid >> 6, lane = tid & 63;
    const int quad = lane >> 4, l16 = lane & 15;
    const int wm = (wave >> 1) * 64;
    const int wn = (wave & 1) * 64;

    f32x4 acc[4][4];
#pragma unroll
    for (int i = 0; i < 4; i++)
#pragma unroll
        for (int j = 0; j < 4; j++) acc[i][j] = (f32x4){0.f, 0.f, 0.f, 0.f};

    // A reg-staging geometry: thread t -> row ar = t>>1 (0..127), half ah = t&1
    const int ar = tid >> 1, ah = tid & 1;
    const float* gAf = A32 + (size_t)(m0 + ar) * K + kbase + ah * 32;

    // B DMA geometry (identical to gemm_bt)
    const int rsub = lane >> 3;
    const int gch = (lane & 7) ^ rsub;
    const unsigned short* gB = Bt + (size_t)(n0 + wave * 32 + rsub) * K + kbase + gch * 8;
    unsigned short* lB[2] = {&Bs[0][wave * 32 * 64], &Bs[1][wave * 32 * 64]};

    // stage A k-chunk [k0, k0+64) of this thread's row into buffer bb
    auto stageA = [&](int k0, int bb) {
#pragma unroll
        for (int c = 0; c < 4; c++) {
            float4 a = *(const float4*)(gAf + k0 + c * 8);
            float4 b = *(const float4*)(gAf + k0 + c * 8 + 4);
            uint4 o;
            o.x = (unsigned int)f2bf(a.x) | ((unsigned int)f2bf(a.y) << 16);
            o.y = (unsigned int)f2bf(a.z) | ((unsigned int)f2bf(a.w) << 16);
            o.z = (unsigned int)f2bf(b.x) | ((unsigned int)f2bf(b.y) << 16);
            o.w = (unsigned int)f2bf(b.z) | ((unsigned int)f2bf(b.w) << 16);
            const int gc = ah * 4 + c;            // global chunk 0..7
            *(uint4*)(&As[bb][ar * 64 + ((gc ^ (ar & 7)) * 8)]) = o;
        }
    };

    // prologue: stage tile 0 into buffer 0
    stageA(0, 0);
#pragma unroll
    for (int j = 0; j < 4; j++)
        async_copy16(gB + (size_t)j * 8 * K, lB[0] + j * 8 * 64);

    const int swz = l16 & 7;
    int buf = 0;
    for (int k0 = 0; k0 < kz; k0 += 64) {
        __syncthreads();   // drains A ds_writes + B DMA (tile k) + reads of buf^1

        const int nk = k0 + 64;
        if (nk < kz) {
            const int nb = buf ^ 1;
            stageA(nk, nb);
#pragma unroll
            for (int j = 0; j < 4; j++)
                async_copy16(gB + nk + (size_t)j * 8 * K, lB[nb] + j * 8 * 64);
        }

        short8 af[2][4], bfr[2][4];
#pragma unroll
        for (int kk = 0; kk < 2; kk++) {
            const int c = kk * 4 + quad;
#pragma unroll
            for (int i = 0; i < 4; i++) {
                af[kk][i]  = *(const short8*)(&As[buf][(wm + i * 16 + l16) * 64 + (c ^ swz) * 8]);
                bfr[kk][i] = *(const short8*)(&Bs[buf][(wn + i * 16 + l16) * 64 + (c ^ swz) * 8]);
            }
        }
#pragma unroll
        for (int kk = 0; kk < 2; kk++)
#pragma unroll
            for (int mi = 0; mi < 4; mi++)
#pragma unroll
                for (int nj = 0; nj < 4; nj++)
                    acc[mi][nj] = __builtin_amdgcn_mfma_f32_16x16x32_bf16(
                        af[kk][mi], bfr[kk][nj], acc[mi][nj], 0, 0, 0);
        buf ^= 1;
    }

    // epilogue: fp32 partial out at z-offset
    float* Cf = Cout + (size_t)blockIdx.z * M * N;
    const int crow0 = m0 + wm + quad * 4;
    const int ccol0 = n0 + wn + l16;
#pragma unroll
    for (int mi = 0; mi < 4; mi++)
#pragma unroll
        for (int i = 0; i < 4; i++) {
            int rr = crow0 + mi * 16 + i;
#pragma unroll
            for (int nj = 0; nj < 4; nj++)
                Cf[(size_t)rr * N + ccol0 + nj * 16] = acc[mi][nj][i];
        }
}

// ---------------------------------------------------------------------------
// conv_ln16s: tap-softmax (2 split-K wscore partials) + causal dynamic conv
// + LayerNorm, 16 t-rows per block (512 blocks). Unchanged from r7 (verified).
// ---------------------------------------------------------------------------
#define XSP 1032   // padded LDS row stride (bf16 elems); 2064B, 16B-aligned
#define WS_STRIDE ((size_t)TB * 256)
__global__ __launch_bounds__(256)
void conv_ln16s(const float* __restrict__ x,
                const float* __restrict__ wscore,
                const float* __restrict__ b_lin,
                const float* __restrict__ ln_g,
                const float* __restrict__ ln_b,
                unsigned short* __restrict__ y) {
    __shared__ __align__(16) unsigned short xs[30 * XSP];   // 60.5 KiB
    __shared__ float wls[16 * 240];                         // 15 KiB
    const int blk = blockIdx.x;          // 0..511
    const int b = blk & 7;
    const int t0 = (blk >> 3) * 16;
    const int tid = threadIdx.x;
    const int wave = tid >> 6, lane = tid & 63;

    // phase 0: stage 30 x-rows, fp32 load + convert, 16B fp32 per thread per row
#pragma unroll
    for (int j = 0; j < 30; j++) {
        const int t = t0 + j - 14;
        uint2 o = make_uint2(0u, 0u);
        if (t >= 0) {
            float4 v = *(const float4*)(x + ((size_t)t * B_DIM + b) * C_DIM + tid * 4);
            o.x = (unsigned int)f2bf(v.x) | ((unsigned int)f2bf(v.y) << 16);
            o.y = (unsigned int)f2bf(v.z) | ((unsigned int)f2bf(v.w) << 16);
        }
        *(uint2*)(&xs[j * XSP + tid * 4]) = o;
    }

    // phase 1: per-(row, head) softmax from 2 split-K partials
    {
        const int row = tid >> 4, hh = tid & 15;
        const size_t grow = (size_t)(t0 + row) * B_DIM + b;
        const float* p = wscore + grow * 256 + hh * K_TAP;
        float v[K_TAP], mx = -1e30f;
#pragma unroll
        for (int k = 0; k < K_TAP; k++) {
            v[k] = p[k] + p[k + WS_STRIDE] + b_lin[hh * K_TAP + k];
            mx = fmaxf(mx, v[k]);
        }
        float s = 0.f;
#pragma unroll
        for (int k = 0; k < K_TAP; k++) { v[k] = __expf(v[k] - mx); s += v[k]; }
        float inv = 1.0f / s;
#pragma unroll
        for (int k = 0; k < K_TAP; k++) wls[row * 240 + hh * K_TAP + k] = v[k] * inv;
    }
    __syncthreads();

    // phase 2: conv + LN. wave handles rows wave, wave+4, wave+8, wave+12.
    const int chA = lane * 8;            // channels [chA, chA+8)
    const int chB = 512 + lane * 8;      // channels [chB, chB+8)
    const int hA = lane >> 3;            // head of chA block
    const int hB = 8 + (lane >> 3);      // head of chB block
    for (int rj = wave; rj < 16; rj += 4) {
        float o[16];
#pragma unroll
        for (int i = 0; i < 16; i++) o[i] = 0.f;
#pragma unroll
        for (int k = 0; k < K_TAP; k++) {
            float wA = wls[rj * 240 + hA * K_TAP + k];
            float wB = wls[rj * 240 + hB * K_TAP + k];
            const unsigned short* xr = &xs[(rj + k) * XSP];
            uint4 pA = *(const uint4*)(xr + chA);
            uint4 pB = *(const uint4*)(xr + chB);
            unsigned int ua[4] = {pA.x, pA.y, pA.z, pA.w};
            unsigned int ub[4] = {pB.x, pB.y, pB.z, pB.w};
#pragma unroll
            for (int q = 0; q < 4; q++) {
                o[2 * q]     += wA * bf2f((unsigned short)(ua[q] & 0xffff));
                o[2 * q + 1] += wA * bf2f((unsigned short)(ua[q] >> 16));
                o[8 + 2 * q]     += wB * bf2f((unsigned short)(ub[q] & 0xffff));
                o[8 + 2 * q + 1] += wB * bf2f((unsigned short)(ub[q] >> 16));
            }
        }
        float s = 0.f, s2 = 0.f;
#pragma unroll
        for (int i = 0; i < 16; i++) { s += o[i]; s2 += o[i] * o[i]; }
#pragma unroll
        for (int off = 32; off > 0; off >>= 1) {
            s  += __shfl_xor(s, off, 64);
            s2 += __shfl_xor(s2, off, 64);
        }
        float mu = s * (1.0f / C_DIM);
        float var = s2 * (1.0f / C_DIM) - mu * mu;
        float rs = rsqrtf(var + 1e-5f);

        unsigned short o16[16];
#pragma unroll
        for (int i = 0; i < 8; i++)
            o16[i] = f2bf((o[i] - mu) * rs * ln_g[chA + i] + ln_b[chA + i]);
#pragma unroll
        for (int i = 0; i < 8; i++)
            o16[8 + i] = f2bf((o[8 + i] - mu) * rs * ln_g[chB + i] + ln_b[chB + i]);
        uint4 w0, w1;
        w0.x = (unsigned int)o16[0]  | ((unsigned int)o16[1]  << 16);
        w0.y = (unsigned int)o16[2]  | ((unsigned int)o16[3]  << 16);
        w0.z = (unsigned int)o16[4]  | ((unsigned int)o16[5]  << 16);
        w0.w = (unsigned int)o16[6]  | ((unsigned int)o16[7]  << 16);
        w1.x = (unsigned int)o16[8]  | ((unsigned int)o16[9]  << 16);
        w1.y = (unsigned int)o16[10] | ((unsigned int)o16[11] << 16);
        w1.z = (unsigned int)o16[12] | ((unsigned int)o16[13] << 16);
        w1.w = (unsigned int)o16[14] | ((unsigned int)o16[15] << 16);
        unsigned short* yr = y + ((size_t)(t0 + rj) * B_DIM + b) * C_DIM;
        *(uint4*)(yr + chA) = w0;
        *(uint4*)(yr + chB) = w1;
    }
}

// ---------------------------------------------------------------------------
extern "C" void kernel_launch(void* const* d_in, const int* in_sizes, int n_in,
                              void* d_out, int out_size, void* d_ws, size_t ws_size,
                              hipStream_t stream) {
    const float* x     = (const float*)d_in[0];
    const float* w_lin = (const float*)d_in[1];
    const float* b_lin = (const float*)d_in[2];
    const float* ln_g  = (const float*)d_in[3];
    const float* ln_b  = (const float*)d_in[4];
    const float* fc1_w = (const float*)d_in[5];
    const float* fc1_b = (const float*)d_in[6];
    const float* fc2_w = (const float*)d_in[7];
    const float* fc2_b = (const float*)d_in[8];
    float* out = (float*)d_out;

    // workspace layout (bytes); ~98 MiB total
    char* ws = (char*)d_ws;
    unsigned short* fc1T  = (unsigned short*)(ws);                      // F x C     8 MiB
    unsigned short* fc2T  = (unsigned short*)(ws + 8388608);            // C x F     8 MiB
    unsigned short* wlinT = (unsigned short*)(ws + 16777216);           // 256 x C   0.5 MiB
    unsigned short* y     = (unsigned short*)(ws + 17301504);           // TB x C   16 MiB
    unsigned short* h     = (unsigned short*)(ws + 34078720);           // TB x F   64 MiB
    // wscore (2 split-K partials) overlaps h's region (dead before fc1)
    float* wscore = (float*)(ws + 34078720);                            // 2 x TB x 256 fp32 (16 MiB)

    // weight transposes (1 launch)
    prep<<<2112, 256, 0, stream>>>(fc1_w, fc1T, fc2_w, fc2T, w_lin, wlinT);

    // conv-weight logits from fp32 x: wscore[z] = x @ wlinT K-slice (z=2, 256 blocks)
    gemm_a32<<<dim3(256 / 128, TB / 128, 2), 256, 0, stream>>>(
        x, wlinT, wscore, TB, 256, C_DIM, C_DIM / 2);

    // fused softmax + dynamic conv + LayerNorm -> y (bf16), 16 rows per block
    conv_ln16s<<<TB / 16, 256, 0, stream>>>(x, wscore, b_lin, ln_g, ln_b, y);

    // h = relu(y @ fc1_w + fc1_b)  (bf16)
    gemm_bt<1, 0><<<dim3(F_DIM / 128, TB / 128, 1), 256, 0, stream>>>(
        y, fc1T, (void*)h, TB, F_DIM, C_DIM, C_DIM, fc1_b, nullptr);

    // out = h @ fc2_w + fc2_b + y  (fp32); m-tile on x for same-XCD h reuse
    gemm_bt<2, 1><<<dim3(TB / 128, C_DIM / 128, 1), 256, 0, stream>>>(
        h, fc2T, (void*)out, TB, C_DIM, F_DIM, F_DIM, fc2_b, y);
}